// Round 12
// baseline (1304.797 us; speedup 1.0000x reference)
//
#include <hip/hip_runtime.h>
#include <cstddef>

typedef __bf16 bf16;
typedef bf16 bf16x4 __attribute__((ext_vector_type(4)));
typedef bf16 bf16x8 __attribute__((ext_vector_type(8)));
typedef float f32x4 __attribute__((ext_vector_type(4)));

#define NLAYER 6
#define HIDD 512
#define SEQL 768
#define NBATCH 16
#define MROWS 12288
#define QKVS 1536

__device__ __forceinline__ void gll16(const void* g, void* l) {
  __builtin_amdgcn_global_load_lds((const __attribute__((address_space(1))) void*)g,
                                   (__attribute__((address_space(3))) void*)l, 16, 0, 0);
}

__device__ __forceinline__ float gelu_f(float v) {
  return 0.5f * v * (1.0f + erff(v * 0.7071067811865475f));
}

#define VMC8 asm volatile("s_waitcnt vmcnt(8)" ::: "memory");
#define VMC4 asm volatile("s_waitcnt vmcnt(4)" ::: "memory");
#define VMC0 asm volatile("s_waitcnt vmcnt(0)" ::: "memory");

// ---------------- prep: weight transposes + lnvec + embed, ONE dispatch ----------------
__global__ __launch_bounds__(256) void prep(
    const float* __restrict__ X, const float* __restrict__ ET,
    const float* __restrict__ Wq, const float* __restrict__ Wk,
    const float* __restrict__ Wv, const float* __restrict__ Wo,
    const float* __restrict__ W1, const float* __restrict__ W2,
    const float* __restrict__ ln1g, const float* __restrict__ ln1b,
    const float* __restrict__ ln2g, const float* __restrict__ ln2b,
    bf16* __restrict__ Wqkvt, bf16* __restrict__ Wot,
    bf16* __restrict__ W1t, bf16* __restrict__ W2t,
    float* __restrict__ vQg, float* __restrict__ vQb,
    float* __restrict__ vW1g, float* __restrict__ vW1b,
    bf16* __restrict__ Zg2) {
  const int bx = blockIdx.x;
  const int t = threadIdx.x;
  if (bx < 18432) {
    const int l = bx / 3072, idx = bx % 3072;
    const float* src;
    bf16* dst;
    int K, N, kb, nb;
    if (idx < 1024) {
      const int which = idx >> 8, tile = idx & 255;
      nb = (tile & 15) * 32; kb = (tile >> 4) * 32; K = 512; N = 512;
      const float* s4[4] = {Wq, Wk, Wv, Wo};
      src = s4[which] + (size_t)l * 512 * 512;
      dst = (which < 3) ? (Wqkvt + (size_t)l * QKVS * 512 + (size_t)which * 512 * 512)
                        : (Wot + (size_t)l * 512 * 512);
    } else if (idx < 2048) {
      const int local = idx - 1024;
      nb = (local & 63) * 32; kb = (local >> 6) * 32; K = 512; N = 2048;
      src = W1 + (size_t)l * 512 * 2048; dst = W1t + (size_t)l * 512 * 2048;
    } else {
      const int local = idx - 2048;
      nb = (local & 15) * 32; kb = (local >> 4) * 32; K = 2048; N = 512;
      src = W2 + (size_t)l * 2048 * 512; dst = W2t + (size_t)l * 2048 * 512;
    }
    __shared__ float tile[32 * 33];
#pragma unroll
    for (int i = 0; i < 4; ++i) {
      int lin = i * 256 + t, r = lin >> 5, c = lin & 31;
      tile[r * 33 + c] = src[(size_t)(kb + r) * N + nb + c];
    }
    __syncthreads();
#pragma unroll
    for (int i = 0; i < 4; ++i) {
      int lin = i * 256 + t, r = lin >> 5, c = lin & 31;
      dst[(size_t)(nb + r) * K + kb + c] = (bf16)tile[c * 33 + r];
    }
    return;
  }
  if (bx < 18432 + 84) {
    const int i = bx - 18432;
    const int l = i / 14;
    const int c = (i % 14) * 256 + t;
    if (c < 1536) {
      float gv = 0.f, bv = 0.f;
      if (l > 0) {
        const float* gin = ln2g + (l - 1) * 512;
        const float* bin = ln2b + (l - 1) * 512;
        const float* W;
        int cc = c;
        if (c < 512) { W = Wq + (size_t)l * 512 * 512; }
        else if (c < 1024) { W = Wk + (size_t)l * 512 * 512; cc = c - 512; }
        else { W = Wv + (size_t)l * 512 * 512; cc = c - 1024; }
        for (int k = 0; k < 512; ++k) {
          const float w = W[(size_t)k * 512 + cc];
          gv += gin[k] * w;
          bv += bin[k] * w;
        }
      }
      vQg[l * 1536 + c] = gv;
      vQb[l * 1536 + c] = bv;
    } else {
      const int cc = c - 1536;
      const float* g1 = ln1g + l * 512;
      const float* b1 = ln1b + l * 512;
      const float* W = W1 + (size_t)l * 512 * 2048;
      float gv = 0.f, bv = 0.f;
      for (int k = 0; k < 512; ++k) {
        const float w = W[(size_t)k * 2048 + cc];
        gv += g1[k] * w;
        bv += b1[k] * w;
      }
      vW1g[l * 2048 + cc] = gv;
      vW1b[l * 2048 + cc] = bv;
    }
    return;
  }
  const int bs = (bx - 18516) * 2 + (t >> 7);
  const int tl = t & 127;
  const int s = bs % SEQL;
  const int b = bs / SEQL;
  const int r = s / 48, c = s % 48;
  float vals[4] = {0.f, 0.f, 0.f, 0.f};
  const int ssrc = s - 1;
  if (ssrc >= 0) {
    const int rs = ssrc / 48, c48 = ssrc % 48;
    const int col = c48 / 3, ch = c48 % 3;
    const float x = X[((b * 3 + ch) * 16 + rs) * 16 + col];
    const int idx = (int)(x * 255.0f) + ch * 256;
    const float sq = 22.62741699796952f;
#pragma unroll
    for (int i = 0; i < 4; ++i) vals[i] = ET[(size_t)idx * HIDD + tl + 128 * i] * sq;
  }
  const float Cc = -0.07252236513366286f;
#pragma unroll
  for (int i = 0; i < 4; ++i) {
    const int d = tl + 128 * i;
    float ts;
    if (d < 128)      ts = sinf((float)r * expf((float)d * Cc));
    else if (d < 256) ts = cosf((float)r * expf((float)(d - 128) * Cc));
    else if (d < 384) ts = sinf((float)c * expf((float)(d - 256) * Cc));
    else              ts = cosf((float)c * expf((float)(d - 384) * Cc));
    Zg2[(size_t)bs * HIDD + d] = (bf16)(vals[i] + ts);
  }
}

// =========================================================================
// 128^2 GEMM, 4-stage single-barrier counted-vmcnt(8) pipeline + setprio.
// [R12: S=4 makes the post-MFMA barrier redundant — STAGE at iter X writes
//  stage (X+2)%4, concurrent readers touch (X-1)%4 / X%4 only. Barriers
//  per K=512: 32 -> 16. LDS 66KB -> 2 blocks/CU (was 3).]
// =========================================================================
template <int EPI, bool L0, int KT>
__global__ __launch_bounds__(256) void gemm2p(const bf16* __restrict__ A,
                                              const bf16* __restrict__ Bt,
                                              bf16* __restrict__ C,
                                              bf16* __restrict__ vT,
                                              const float* __restrict__ pIn,
                                              const float* __restrict__ vg,
                                              const float* __restrict__ vb,
                                              const float* __restrict__ bias,
                                              int N) {
  constexpr int K = KT;
  constexpr int NI = K >> 5;
  __shared__ char sbuf[65536];  // 4 stages x (A 8KB | B 8KB)
  __shared__ float rsL[128], rsmL[128];
  const int tid = threadIdx.x;
  const int lane = tid & 63, w = tid >> 6;
  const int wr = w >> 1, wc = w & 1;
  const int l15 = lane & 15, g = lane >> 4;
  const int m0 = blockIdx.y * 128, n0 = blockIdx.x * 128;
  f32x4 acc[4][4] = {};
  const int rr0 = tid >> 2, kc = tid & 3;
  const bf16* Ap0 = A + (size_t)(m0 + rr0) * K + kc * 8;
  const bf16* Ap1 = A + (size_t)(m0 + 64 + rr0) * K + kc * 8;
  const bf16* Bp0 = Bt + (size_t)(n0 + rr0) * K + kc * 8;
  const bf16* Bp1 = Bt + (size_t)(n0 + 64 + rr0) * K + kc * 8;

  auto STAGE = [&](int st, int kt) {
    char* base = sbuf + st * 16384;
    gll16(Ap0 + kt, base + tid * 16);
    gll16(Ap1 + kt, base + 4096 + tid * 16);
    gll16(Bp0 + kt, base + 8192 + tid * 16);
    gll16(Bp1 + kt, base + 12288 + tid * 16);
  };

  STAGE(0, 0);
  STAGE(1, 32);
#pragma unroll 4
  for (int it = 0; it < NI; ++it) {
    const int cur = it & 3;
    if (it + 2 < NI) {
      STAGE((it + 2) & 3, (it + 2) * 32);
      VMC8;
    } else if (it + 1 < NI) {
      VMC4;
    } else {
      VMC0;
    }
    __builtin_amdgcn_s_barrier();
    const char* base = sbuf + cur * 16384;
    bf16x8 af[4], bv[4];
#pragma unroll
    for (int i = 0; i < 4; ++i)
      af[i] = *(const bf16x8*)(base + ((wr * 64 + i * 16 + l15) * 32 + 8 * g) * 2);
#pragma unroll
    for (int i = 0; i < 4; ++i)
      bv[i] = *(const bf16x8*)(base + 8192 + ((wc * 64 + i * 16 + l15) * 32 + 8 * g) * 2);
    __builtin_amdgcn_s_setprio(1);
#pragma unroll
    for (int mi = 0; mi < 4; ++mi)
#pragma unroll
      for (int ni = 0; ni < 4; ++ni)
        acc[mi][ni] = __builtin_amdgcn_mfma_f32_16x16x32_bf16(af[mi], bv[ni], acc[mi][ni], 0, 0, 0);
    __builtin_amdgcn_s_setprio(0);
    // no trailing barrier: S=4 makes next iteration's STAGE target disjoint
  }

  if constexpr (!L0) {
    if (tid < 128) {
      const int row = m0 + tid;
      float s = 0.f, q = 0.f;
#pragma unroll
      for (int j = 0; j < 8; ++j) {
        s += pIn[(size_t)j * MROWS + row];
        q += pIn[(size_t)(8 + j) * MROWS + row];
      }
      const float mean = s * (1.0f / 512.0f);
      const float var = q * (1.0f / 512.0f) - mean * mean;
      const float rs = rsqrtf(var + 1e-6f);
      rsL[tid] = rs;
      rsmL[tid] = rs * mean;
    }
    __syncthreads();
  }

  const bool VPATH = (EPI == 0) && (n0 >= 1024);
#pragma unroll
  for (int mi = 0; mi < 4; ++mi)
#pragma unroll
    for (int nf = 0; nf < 4; ++nf) {
      const int lr = wr * 64 + mi * 16 + 4 * g;
      const int row = m0 + lr;
      const int col = n0 + wc * 64 + nf * 16 + l15;
      float vgc = 0.f, vbc = 0.f, bc = 0.f;
      if constexpr (!L0) { vgc = vg[col]; vbc = vb[col]; }
      if constexpr (EPI == 1) bc = bias[col];
      float val[4];
#pragma unroll
      for (int r = 0; r < 4; ++r) {
        float a = acc[mi][nf][r];
        float v;
        if constexpr (L0) v = a;
        else v = rsL[lr + r] * a - rsmL[lr + r] * vgc + vbc;
        if constexpr (EPI == 1) v = gelu_f(v + bc);
        val[r] = v;
      }
      if (VPATH) {
        const int cv = col - 1024, hh = cv >> 6, dd = cv & 63;
        const int b = row / SEQL, s = row % SEQL;
        bf16x4 q4;
#pragma unroll
        for (int r = 0; r < 4; ++r) q4[r] = (bf16)val[r];
        *(bf16x4*)&vT[(size_t)((b * 8 + hh) * 64 + dd) * SEQL + s] = q4;
      } else {
#pragma unroll
        for (int r = 0; r < 4; ++r)
          C[(size_t)(row + r) * N + col] = (bf16)val[r];
      }
    }
}

// =========================================================================
// 128^2 GEMM, 4-stage single-barrier, LN-fused epilogue (Wo / FFN2).
// =========================================================================
template <int EPI, int KT>
__global__ __launch_bounds__(256) void gemm_fuse(const bf16* __restrict__ A,
                                                 const bf16* __restrict__ Bt,
                                                 const bf16* __restrict__ zgIn,
                                                 const float* __restrict__ pIn,
                                                 const float* __restrict__ vg_in,
                                                 const float* __restrict__ vb_in,
                                                 const float* __restrict__ extra_b,
                                                 const float* __restrict__ g_out,
                                                 bf16* __restrict__ zgOut,
                                                 float* __restrict__ pOut) {
  constexpr int N = 512;
  constexpr int K = KT;
  constexpr int NI = K >> 5;
  __shared__ char sbuf[65536];
  __shared__ float rsL[128], rsmL[128];
  const int tid = threadIdx.x;
  const int lane = tid & 63, w = tid >> 6;
  const int wr = w >> 1, wc = w & 1;
  const int l15 = lane & 15, g = lane >> 4;
  const int m0 = blockIdx.y * 128, n0 = blockIdx.x * 128;
  f32x4 acc[4][4] = {};
  const int rr0 = tid >> 2, kc = tid & 3;
  const bf16* Ap0 = A + (size_t)(m0 + rr0) * K + kc * 8;
  const bf16* Ap1 = A + (size_t)(m0 + 64 + rr0) * K + kc * 8;
  const bf16* Bp0 = Bt + (size_t)(n0 + rr0) * K + kc * 8;
  const bf16* Bp1 = Bt + (size_t)(n0 + 64 + rr0) * K + kc * 8;

  auto STAGE = [&](int st, int kt) {
    char* base = sbuf + st * 16384;
    gll16(Ap0 + kt, base + tid * 16);
    gll16(Ap1 + kt, base + 4096 + tid * 16);
    gll16(Bp0 + kt, base + 8192 + tid * 16);
    gll16(Bp1 + kt, base + 12288 + tid * 16);
  };

  STAGE(0, 0);
  STAGE(1, 32);
#pragma unroll 4
  for (int it = 0; it < NI; ++it) {
    const int cur = it & 3;
    if (it + 2 < NI) {
      STAGE((it + 2) & 3, (it + 2) * 32);
      VMC8;
    } else if (it + 1 < NI) {
      VMC4;
    } else {
      VMC0;
    }
    __builtin_amdgcn_s_barrier();
    const char* base = sbuf + cur * 16384;
    bf16x8 af[4], bv[4];
#pragma unroll
    for (int i = 0; i < 4; ++i)
      af[i] = *(const bf16x8*)(base + ((wr * 64 + i * 16 + l15) * 32 + 8 * g) * 2);
#pragma unroll
    for (int i = 0; i < 4; ++i)
      bv[i] = *(const bf16x8*)(base + 8192 + ((wc * 64 + i * 16 + l15) * 32 + 8 * g) * 2);
    __builtin_amdgcn_s_setprio(1);
#pragma unroll
    for (int mi = 0; mi < 4; ++mi)
#pragma unroll
      for (int ni = 0; ni < 4; ++ni)
        acc[mi][ni] = __builtin_amdgcn_mfma_f32_16x16x32_bf16(af[mi], bv[ni], acc[mi][ni], 0, 0, 0);
    __builtin_amdgcn_s_setprio(0);
  }
  __syncthreads();  // all waves done reading sbuf before ztile reuses it

  bf16* ztile = (bf16*)sbuf;
#pragma unroll
  for (int j = 0; j < 8; ++j) {
    const int row = j * 16 + (tid >> 4);
    const bf16* gsrc = zgIn + (size_t)(m0 + row) * N + n0 + (tid & 15) * 8;
    gll16(gsrc, sbuf + j * 4096 + tid * 16);
  }

  if constexpr (EPI != 0) {
    if (tid < 128) {
      const int row = m0 + tid;
      float s = 0.f, q = 0.f;
#pragma unroll
      for (int j = 0; j < 8; ++j) {
        s += pIn[(size_t)j * MROWS + row];
        q += pIn[(size_t)(8 + j) * MROWS + row];
      }
      const float mean = s * (1.0f / 512.0f);
      const float var = q * (1.0f / 512.0f) - mean * mean;
      const float rs = rsqrtf(var + 1e-6f);
      rsL[tid] = rs;
      rsmL[tid] = rs * mean;
    }
  }
  VMC0;
  __syncthreads();

  const int nb = n0 >> 7;
  float vgc[4], vbc[4], go[4], eb[4];
#pragma unroll
  for (int ni = 0; ni < 4; ++ni) {
    const int col = n0 + wc * 64 + ni * 16 + l15;
    if constexpr (EPI != 0) { vgc[ni] = vg_in[col]; vbc[ni] = vb_in[col]; }
    go[ni] = g_out[col];
    if constexpr (EPI == 2) eb[ni] = extra_b[col];
  }
#pragma unroll
  for (int mi = 0; mi < 4; ++mi) {
#pragma unroll
    for (int rr = 0; rr < 4; ++rr) {
      const int lr = wr * 64 + mi * 16 + 4 * g + rr;
      const int row = m0 + lr;
      float s = 0.f, q = 0.f;
#pragma unroll
      for (int ni = 0; ni < 4; ++ni) {
        const int lc = wc * 64 + ni * 16 + l15;
        const float zgv = (float)ztile[lr * 128 + lc];
        float hprev;
        if constexpr (EPI == 0) hprev = zgv;
        else hprev = rsL[lr] * zgv - rsmL[lr] * vgc[ni] + vbc[ni];
        float z = acc[mi][ni][rr] + hprev;
        if constexpr (EPI == 2) z += eb[ni];
        s += z;
        q += z * z;
        ztile[lr * 128 + lc] = (bf16)(z * go[ni]);
      }
      s += __shfl_xor(s, 1); s += __shfl_xor(s, 2); s += __shfl_xor(s, 4); s += __shfl_xor(s, 8);
      q += __shfl_xor(q, 1); q += __shfl_xor(q, 2); q += __shfl_xor(q, 4); q += __shfl_xor(q, 8);
      if (l15 == 0) {
        pOut[(size_t)(nb * 2 + wc) * MROWS + row] = s;
        pOut[(size_t)(8 + nb * 2 + wc) * MROWS + row] = q;
      }
    }
  }
  __syncthreads();
#pragma unroll
  for (int i = 0; i < 8; ++i) {
    const int id = i * 256 + tid;
    const int row = id >> 4, c16 = id & 15;
    bf16x8 v = *(const bf16x8*)&ztile[row * 128 + c16 * 8];
    *(bf16x8*)&zgOut[(size_t)(m0 + row) * N + n0 + c16 * 8] = v;
  }
}

// =========================================================================
// Local attention: K/V tiles staged to LDS (coalesced + source-swizzled),
// P chunked through 10KB LDS. 74KB LDS -> 2 WGs/CU. (verified round-9)
// =========================================================================
template <int NKEY>
__device__ __forceinline__ void attn_body(int n, int h, int b,
                                          const bf16* __restrict__ Qb,
                                          const bf16* __restrict__ Kb,
                                          const bf16* __restrict__ Vt,
                                          bf16* __restrict__ O,
                                          bf16* __restrict__ Ks,
                                          bf16* __restrict__ Vs,
                                          bf16* __restrict__ Pc) {
  constexpr int NF = NKEY / 16;
  constexpr int KC = NKEY / 32;
  constexpr int VG = NKEY / 8;
  const int tid = threadIdx.x, w = tid >> 6, lane = tid & 63;
  const int l15 = lane & 15, g = lane >> 4;
  const int keybase = (NKEY == 128) ? 0 : (n - 1) * 128;
  const int qbase = n * 128;

#pragma unroll
  for (int p = 0; p < NKEY / 64; ++p) {
    const int j = p * 512 + tid;
    const int row = j >> 3, lg = j & 7;
    const int pg = lg ^ (row & 7);
    gll16(Kb + (size_t)(b * SEQL + keybase + row) * QKVS + h * 64 + pg * 8, Ks + j * 8);
  }
#pragma unroll
  for (int p = 0; p < NKEY / 64; ++p) {
    const int j = p * 512 + tid;
    const int row = j / VG, lg = j % VG;
    const int pg = lg ^ (row & (VG - 1));
    gll16(Vt + (size_t)((b * 8 + h) * 64 + row) * SEQL + keybase + pg * 8, Vs + j * 8);
  }

  const bf16* qrow = Qb + (size_t)(b * SEQL + qbase + w * 16 + l15) * QKVS + h * 64;
  bf16x8 qf0 = *(const bf16x8*)(qrow + 8 * g);
  bf16x8 qf1 = *(const bf16x8*)(qrow + 32 + 8 * g);

  VMC0;
  __syncthreads();

  f32x4 S[NF];
#pragma unroll
  for (int nf = 0; nf < NF; ++nf) S[nf] = f32x4{0.f, 0.f, 0.f, 0.f};
#pragma unroll
  for (int nf = 0; nf < NF; ++nf) {
    const int krow = nf * 16 + l15;
    const int pg0 = g ^ (krow & 7);
    const int pg1 = (g + 4) ^ (krow & 7);
    bf16x8 kf0 = *(const bf16x8*)&Ks[krow * 64 + pg0 * 8];
    bf16x8 kf1 = *(const bf16x8*)&Ks[krow * 64 + pg1 * 8];
    S[nf] = __builtin_amdgcn_mfma_f32_16x16x32_bf16(qf0, kf0, S[nf], 0, 0, 0);
    S[nf] = __builtin_amdgcn_mfma_f32_16x16x32_bf16(qf1, kf1, S[nf], 0, 0, 0);
  }
#pragma unroll
  for (int rr = 0; rr < 4; ++rr) {
    const int qloc = w * 16 + 4 * g + rr;
    float mx = -3.0e38f;
#pragma unroll
    for (int nf = 0; nf < NF; ++nf) {
      const int key = nf * 16 + l15;
      const bool valid = (NKEY == 128) ? (key <= qloc) : (key <= qloc + 128);
      float v = valid ? S[nf][rr] * 0.125f : -1.0e9f;
      S[nf][rr] = v;
      mx = fmaxf(mx, v);
    }
    mx = fmaxf(mx, __shfl_xor(mx, 1));
    mx = fmaxf(mx, __shfl_xor(mx, 2));
    mx = fmaxf(mx, __shfl_xor(mx, 4));
    mx = fmaxf(mx, __shfl_xor(mx, 8));
    float sden = 0.f;
#pragma unroll
    for (int nf = 0; nf < NF; ++nf) {
      float e = expf(S[nf][rr] - mx);
      S[nf][rr] = e;
      sden += e;
    }
    sden += __shfl_xor(sden, 1);
    sden += __shfl_xor(sden, 2);
    sden += __shfl_xor(sden, 4);
    sden += __shfl_xor(sden, 8);
    const float rcp = 1.0f / sden;
#pragma unroll
    for (int nf = 0; nf < NF; ++nf) S[nf][rr] *= rcp;
  }

  bf16* pcw = Pc + w * 640;
  f32x4 Oacc[4];
#pragma unroll
  for (int i = 0; i < 4; ++i) Oacc[i] = f32x4{0.f, 0.f, 0.f, 0.f};
#pragma unroll
  for (int kc = 0; kc < KC; ++kc) {
#pragma unroll
    for (int rr = 0; rr < 4; ++rr) {
      pcw[(4 * g + rr) * 40 + l15] = (bf16)S[2 * kc][rr];
      pcw[(4 * g + rr) * 40 + 16 + l15] = (bf16)S[2 * kc + 1][rr];
    }
    bf16x8 pa = *(const bf16x8*)&pcw[l15 * 40 + 8 * g];
#pragma unroll
    for (int nf = 0; nf < 4; ++nf) {
      const int vrow = nf * 16 + l15;
      const int pg = (kc * 4 + g) ^ (vrow & (VG - 1));
      bf16x8 vf = *(const bf16x8*)&Vs[vrow * NKEY + pg * 8];
      Oacc[nf] = __builtin_amdgcn_mfma_f32_16x16x32_bf16(pa, vf, Oacc[nf], 0, 0, 0);
    }
  }
#pragma unroll
  for (int nf = 0; nf < 4; ++nf)
#pragma unroll
    for (int rr = 0; rr < 4; ++rr)
      O[(size_t)(b * SEQL + qbase + w * 16 + 4 * g + rr) * HIDD + h * 64 + nf * 16 + l15] =
          (bf16)Oacc[nf][rr];
}

__global__ __launch_bounds__(512, 4) void attn_all(const bf16* __restrict__ Qb,
                                                   const bf16* __restrict__ Kb,
                                                   const bf16* __restrict__ Vt,
                                                   bf16* __restrict__ O) {
  __shared__ bf16 Ks[256 * 64];
  __shared__ bf16 Vs[64 * 256];
  __shared__ bf16 Pc[8 * 640];
  const int n = blockIdx.x, h = blockIdx.y, b = blockIdx.z;
  if (n == 0)
    attn_body<128>(0, h, b, Qb, Kb, Vt, O, Ks, Vs, Pc);
  else
    attn_body<256>(n, h, b, Qb, Kb, Vt, O, Ks, Vs, Pc);
}

// ---------------- final projection (input = recon LN of zg2) ----------------
__global__ __launch_bounds__(256) void proj_partial(const bf16* __restrict__ zg2,
                                                    const float* __restrict__ pSQ2,
                                                    const float* __restrict__ g5,
                                                    const float* __restrict__ b5,
                                                    const float* __restrict__ W,
                                                    float* __restrict__ part) {
  const int kc = blockIdx.x;
  const int t = threadIdx.x;
  __shared__ float Al[512 * 20];
  __shared__ float gld[512], bld[512], rsP[16], rsmP[16];
  gld[t] = g5[t]; gld[t + 256] = g5[t + 256];
  bld[t] = b5[t]; bld[t + 256] = b5[t + 256];
  if (t < 16) {
    const int row = t * SEQL + kc;
    float s = 0.f, q = 0.f;
#pragma unroll
    for (int j = 0; j < 8; ++j) {
      s += pSQ2[(size_t)j * MROWS + row];
      q += pSQ2[(size_t)(8 + j) * MROWS + row];
    }
    const float mean = s * (1.0f / 512.0f);
    const float var = q * (1.0f / 512.0f) - mean * mean;
    const float rs = rsqrtf(var + 1e-6f);
    rsP[t] = rs;
    rsmP[t] = rs * mean;
  }
  __syncthreads();
#pragma unroll
  for (int i = 0; i < 32; ++i) {
    int lin = i * 256 + t, m = lin >> 9, kk = lin & 511;
    const int row = m * SEQL + kc;
    Al[kk * 20 + m] = rsP[m] * (float)zg2[(size_t)row * 512 + kk] - rsmP[m] * gld[kk] + bld[kk];
  }
  __syncthreads();
  const size_t k0 = (size_t)kc * 512;
  float acc[16] = {};
  for (int kk = 0; kk < 512; ++kk) {
    const float wv = W[(k0 + kk) * 256 + t];
    const f32x4* a = (const f32x4*)&Al[kk * 20];
#pragma unroll
    for (int j = 0; j < 4; ++j) {
      f32x4 av = a[j];
      acc[j * 4 + 0] += av[0] * wv;
      acc[j * 4 + 1] += av[1] * wv;
      acc[j * 4 + 2] += av[2] * wv;
      acc[j * 4 + 3] += av[3] * wv;
    }
  }
#pragma unroll
  for (int m = 0; m < 16; ++m) part[(size_t)kc * 4096 + m * 256 + t] = acc[m];
}

// merged reduce + gelu + LN over 256 outputs per row
__global__ __launch_bounds__(256) void proj_tail(const float* __restrict__ part,
                                                 const float* __restrict__ g,
                                                 const float* __restrict__ bt,
                                                 float* __restrict__ out) {
  const int row = blockIdx.x, t = threadIdx.x;
  float v = 0.f;
  for (int c = 0; c < 768; ++c) v += part[(size_t)c * 4096 + row * 256 + t];
  const float x = gelu_f(v);
  __shared__ float red[256];
  red[t] = x;
  __syncthreads();
  for (int off = 128; off > 0; off >>= 1) {
    if (t < off) red[t] += red[t + off];
    __syncthreads();
  }
  const float mean = red[0] * (1.0f / 256.0f);
  __syncthreads();
  const float dx = x - mean;
  red[t] = dx * dx;
  __syncthreads();
  for (int off = 128; off > 0; off >>= 1) {
    if (t < off) red[t] += red[t + off];
    __syncthreads();
  }
  const float var = red[0] * (1.0f / 256.0f);
  const float rs = rsqrtf(var + 1e-6f);
  out[row * 256 + t] = dx * rs * g[t] + bt[t];
}

extern "C" void kernel_launch(void* const* d_in, const int* in_sizes, int n_in,
                              void* d_out, int out_size, void* d_ws, size_t ws_size,
                              hipStream_t stream) {
  const float* X = (const float*)d_in[0];
  const float* ET = (const float*)d_in[1];
  const float* Wq = (const float*)d_in[2];
  const float* Wk = (const float*)d_in[3];
  const float* Wv = (const float*)d_in[4];
  const float* Wo = (const float*)d_in[5];
  const float* ln1g = (const float*)d_in[6];
  const float* ln1b = (const float*)d_in[7];
  const float* W1 = (const float*)d_in[8];
  const float* b1 = (const float*)d_in[9];
  const float* W2 = (const float*)d_in[10];
  const float* b2 = (const float*)d_in[11];
  const float* ln2g = (const float*)d_in[12];
  const float* ln2b = (const float*)d_in[13];
  const float* PW = (const float*)d_in[14];
  const float* og = (const float*)d_in[15];
  const float* obv = (const float*)d_in[16];
  float* out = (float*)d_out;

  char* p = (char*)d_ws;
  auto alloc = [&](size_t bytes) {
    char* r = p;
    p += (bytes + 255) & ~(size_t)255;
    return r;
  };
  bf16* Wqkvt = (bf16*)alloc((size_t)NLAYER * QKVS * 512 * 2);
  bf16* Wot = (bf16*)alloc((size_t)NLAYER * 512 * 512 * 2);
  bf16* W1t = (bf16*)alloc((size_t)NLAYER * 512 * 2048 * 2);
  bf16* W2t = (bf16*)alloc((size_t)NLAYER * 512 * 2048 * 2);
  float* vQg = (float*)alloc((size_t)NLAYER * QKVS * 4);
  float* vQb = (float*)alloc((size_t)NLAYER * QKVS * 4);
  float* vW1g = (float*)alloc((size_t)NLAYER * 2048 * 4);
  float* vW1b = (float*)alloc((size_t)NLAYER * 2048 * 4);
  bf16* zg2 = (bf16*)alloc((size_t)MROWS * HIDD * 2);
  bf16* zg1 = (bf16*)alloc((size_t)MROWS * HIDD * 2);
  float* pSQ1 = (float*)alloc((size_t)16 * MROWS * 4);
  float* pSQ2 = (float*)alloc((size_t)16 * MROWS * 4);
  bf16* qkvB = (bf16*)alloc((size_t)MROWS * QKVS * 2);
  bf16* vT = (bf16*)alloc((size_t)MROWS * HIDD * 2);
  bf16* aO = (bf16*)alloc((size_t)MROWS * HIDD * 2);
  bf16* mid = (bf16*)alloc((size_t)MROWS * 2048 * 2);
  float* part = (float*)alloc((size_t)768 * 4096 * 4);
  (void)ws_size; (void)n_in; (void)in_sizes; (void)out_size;

  prep<<<24660, 256, 0, stream>>>(X, ET, Wq, Wk, Wv, Wo, W1, W2, ln1g, ln1b, ln2g, ln2b,
                                  Wqkvt, Wot, W1t, W2t, vQg, vQb, vW1g, vW1b, zg2);

  for (int i = 0; i < NLAYER; ++i) {
    const bf16* WqkvL = Wqkvt + (size_t)i * QKVS * 512;
    const bf16* WoL = Wot + (size_t)i * 512 * 512;
    const bf16* W1L = W1t + (size_t)i * 512 * 2048;
    const bf16* W2L = W2t + (size_t)i * 512 * 2048;
    if (i == 0)
      gemm2p<0, true, 512><<<dim3(12, 96), 256, 0, stream>>>(zg2, WqkvL, qkvB, vT, pSQ2,
                                                             vQg, vQb, nullptr, QKVS);
    else
      gemm2p<0, false, 512><<<dim3(12, 96), 256, 0, stream>>>(zg2, WqkvL, qkvB, vT, pSQ2,
                                                              vQg + i * QKVS, vQb + i * QKVS,
                                                              nullptr, QKVS);
    attn_all<<<dim3(6, 8, 16), 512, 0, stream>>>(qkvB, qkvB + 512, vT, aO);
    if (i == 0)
      gemm_fuse<0, 512><<<dim3(4, 96), 256, 0, stream>>>(aO, WoL, zg2, nullptr, nullptr,
                                                         nullptr, nullptr, ln1g, zg1, pSQ1);
    else
      gemm_fuse<1, 512><<<dim3(4, 96), 256, 0, stream>>>(aO, WoL, zg2, pSQ2,
                                                         ln2g + (i - 1) * 512,
                                                         ln2b + (i - 1) * 512, nullptr,
                                                         ln1g + i * 512, zg1, pSQ1);
    gemm2p<1, false, 512><<<dim3(16, 96), 256, 0, stream>>>(zg1, W1L, mid, nullptr, pSQ1,
                                                            vW1g + i * 2048, vW1b + i * 2048,
                                                            b1 + i * 2048, 2048);
    gemm_fuse<2, 2048><<<dim3(4, 96), 256, 0, stream>>>(mid, W2L, zg1, pSQ1, ln1g + i * 512,
                                                        ln1b + i * 512, b2 + i * 512,
                                                        ln2g + i * 512, zg2, pSQ2);
  }

  proj_partial<<<768, 256, 0, stream>>>(zg2, pSQ2, ln2g + 5 * 512, ln2b + 5 * 512, PW, part);
  proj_tail<<<16, 256, 0, stream>>>(part, og, obv, out);
}

// Round 13
// 1243.450 us; speedup vs baseline: 1.0493x; 1.0493x over previous
//
#include <hip/hip_runtime.h>
#include <cstddef>

typedef __bf16 bf16;
typedef bf16 bf16x4 __attribute__((ext_vector_type(4)));
typedef bf16 bf16x8 __attribute__((ext_vector_type(8)));
typedef float f32x4 __attribute__((ext_vector_type(4)));

#define NLAYER 6
#define HIDD 512
#define SEQL 768
#define NBATCH 16
#define MROWS 12288
#define QKVS 1536

__device__ __forceinline__ void gll16(const void* g, void* l) {
  __builtin_amdgcn_global_load_lds((const __attribute__((address_space(1))) void*)g,
                                   (__attribute__((address_space(3))) void*)l, 16, 0, 0);
}

__device__ __forceinline__ float gelu_f(float v) {
  return 0.5f * v * (1.0f + erff(v * 0.7071067811865475f));
}

#define VMC8 asm volatile("s_waitcnt vmcnt(8)" ::: "memory");
#define VMC4 asm volatile("s_waitcnt vmcnt(4)" ::: "memory");
#define VMC0 asm volatile("s_waitcnt vmcnt(0)" ::: "memory");

// ---------------- prep: weight transposes + lnvec + embed, ONE dispatch ----------------
__global__ __launch_bounds__(256) void prep(
    const float* __restrict__ X, const float* __restrict__ ET,
    const float* __restrict__ Wq, const float* __restrict__ Wk,
    const float* __restrict__ Wv, const float* __restrict__ Wo,
    const float* __restrict__ W1, const float* __restrict__ W2,
    const float* __restrict__ ln1g, const float* __restrict__ ln1b,
    const float* __restrict__ ln2g, const float* __restrict__ ln2b,
    bf16* __restrict__ Wqkvt, bf16* __restrict__ Wot,
    bf16* __restrict__ W1t, bf16* __restrict__ W2t,
    float* __restrict__ vQg, float* __restrict__ vQb,
    float* __restrict__ vW1g, float* __restrict__ vW1b,
    bf16* __restrict__ Zg2) {
  const int bx = blockIdx.x;
  const int t = threadIdx.x;
  if (bx < 18432) {
    const int l = bx / 3072, idx = bx % 3072;
    const float* src;
    bf16* dst;
    int K, N, kb, nb;
    if (idx < 1024) {
      const int which = idx >> 8, tile = idx & 255;
      nb = (tile & 15) * 32; kb = (tile >> 4) * 32; K = 512; N = 512;
      const float* s4[4] = {Wq, Wk, Wv, Wo};
      src = s4[which] + (size_t)l * 512 * 512;
      dst = (which < 3) ? (Wqkvt + (size_t)l * QKVS * 512 + (size_t)which * 512 * 512)
                        : (Wot + (size_t)l * 512 * 512);
    } else if (idx < 2048) {
      const int local = idx - 1024;
      nb = (local & 63) * 32; kb = (local >> 6) * 32; K = 512; N = 2048;
      src = W1 + (size_t)l * 512 * 2048; dst = W1t + (size_t)l * 512 * 2048;
    } else {
      const int local = idx - 2048;
      nb = (local & 15) * 32; kb = (local >> 4) * 32; K = 2048; N = 512;
      src = W2 + (size_t)l * 2048 * 512; dst = W2t + (size_t)l * 2048 * 512;
    }
    __shared__ float tile[32 * 33];
#pragma unroll
    for (int i = 0; i < 4; ++i) {
      int lin = i * 256 + t, r = lin >> 5, c = lin & 31;
      tile[r * 33 + c] = src[(size_t)(kb + r) * N + nb + c];
    }
    __syncthreads();
#pragma unroll
    for (int i = 0; i < 4; ++i) {
      int lin = i * 256 + t, r = lin >> 5, c = lin & 31;
      dst[(size_t)(nb + r) * K + kb + c] = (bf16)tile[c * 33 + r];
    }
    return;
  }
  if (bx < 18432 + 84) {
    const int i = bx - 18432;
    const int l = i / 14;
    const int c = (i % 14) * 256 + t;
    if (c < 1536) {
      float gv = 0.f, bv = 0.f;
      if (l > 0) {
        const float* gin = ln2g + (l - 1) * 512;
        const float* bin = ln2b + (l - 1) * 512;
        const float* W;
        int cc = c;
        if (c < 512) { W = Wq + (size_t)l * 512 * 512; }
        else if (c < 1024) { W = Wk + (size_t)l * 512 * 512; cc = c - 512; }
        else { W = Wv + (size_t)l * 512 * 512; cc = c - 1024; }
        for (int k = 0; k < 512; ++k) {
          const float w = W[(size_t)k * 512 + cc];
          gv += gin[k] * w;
          bv += bin[k] * w;
        }
      }
      vQg[l * 1536 + c] = gv;
      vQb[l * 1536 + c] = bv;
    } else {
      const int cc = c - 1536;
      const float* g1 = ln1g + l * 512;
      const float* b1 = ln1b + l * 512;
      const float* W = W1 + (size_t)l * 512 * 2048;
      float gv = 0.f, bv = 0.f;
      for (int k = 0; k < 512; ++k) {
        const float w = W[(size_t)k * 2048 + cc];
        gv += g1[k] * w;
        bv += b1[k] * w;
      }
      vW1g[l * 2048 + cc] = gv;
      vW1b[l * 2048 + cc] = bv;
    }
    return;
  }
  const int bs = (bx - 18516) * 2 + (t >> 7);
  const int tl = t & 127;
  const int s = bs % SEQL;
  const int b = bs / SEQL;
  const int r = s / 48, c = s % 48;
  float vals[4] = {0.f, 0.f, 0.f, 0.f};
  const int ssrc = s - 1;
  if (ssrc >= 0) {
    const int rs = ssrc / 48, c48 = ssrc % 48;
    const int col = c48 / 3, ch = c48 % 3;
    const float x = X[((b * 3 + ch) * 16 + rs) * 16 + col];
    const int idx = (int)(x * 255.0f) + ch * 256;
    const float sq = 22.62741699796952f;
#pragma unroll
    for (int i = 0; i < 4; ++i) vals[i] = ET[(size_t)idx * HIDD + tl + 128 * i] * sq;
  }
  const float Cc = -0.07252236513366286f;
#pragma unroll
  for (int i = 0; i < 4; ++i) {
    const int d = tl + 128 * i;
    float ts;
    if (d < 128)      ts = sinf((float)r * expf((float)d * Cc));
    else if (d < 256) ts = cosf((float)r * expf((float)(d - 128) * Cc));
    else if (d < 384) ts = sinf((float)c * expf((float)(d - 256) * Cc));
    else              ts = cosf((float)c * expf((float)(d - 384) * Cc));
    Zg2[(size_t)bs * HIDD + d] = (bf16)(vals[i] + ts);
  }
}

// =========================================================================
// 128^2 GEMM, 3-stage dbuf counted-vmcnt(8) pipeline, LN-affine epilogue.
// [R13: verified optimum — 3 blocks/CU, 12 waves/CU. All four structural
//  alternatives regressed: 256^2 8-phase, BN=512 fusion, 128x256 reg-block,
//  4-stage single-barrier. Occupancy dominates at these K=512 shapes.]
// =========================================================================
template <int EPI, bool L0, int KT>
__global__ __launch_bounds__(256) void gemm2p(const bf16* __restrict__ A,
                                              const bf16* __restrict__ Bt,
                                              bf16* __restrict__ C,
                                              bf16* __restrict__ vT,
                                              const float* __restrict__ pIn,
                                              const float* __restrict__ vg,
                                              const float* __restrict__ vb,
                                              const float* __restrict__ bias,
                                              int N) {
  constexpr int K = KT;
  constexpr int NI = K >> 5;
  __shared__ char sbuf[49152];
  __shared__ float rsL[128], rsmL[128];
  const int tid = threadIdx.x;
  const int lane = tid & 63, w = tid >> 6;
  const int wr = w >> 1, wc = w & 1;
  const int l15 = lane & 15, g = lane >> 4;
  const int m0 = blockIdx.y * 128, n0 = blockIdx.x * 128;
  f32x4 acc[4][4] = {};
  const int rr0 = tid >> 2, kc = tid & 3;
  const bf16* Ap0 = A + (size_t)(m0 + rr0) * K + kc * 8;
  const bf16* Ap1 = A + (size_t)(m0 + 64 + rr0) * K + kc * 8;
  const bf16* Bp0 = Bt + (size_t)(n0 + rr0) * K + kc * 8;
  const bf16* Bp1 = Bt + (size_t)(n0 + 64 + rr0) * K + kc * 8;

  auto STAGE = [&](int st, int kt) {
    char* base = sbuf + st * 16384;
    gll16(Ap0 + kt, base + tid * 16);
    gll16(Ap1 + kt, base + 4096 + tid * 16);
    gll16(Bp0 + kt, base + 8192 + tid * 16);
    gll16(Bp1 + kt, base + 12288 + tid * 16);
  };

  STAGE(0, 0);
  STAGE(1, 32);
#pragma unroll 3
  for (int it = 0; it < NI; ++it) {
    const int cur = it % 3;
    if (it + 2 < NI) {
      STAGE((it + 2) % 3, (it + 2) * 32);
      VMC8;
    } else if (it + 1 < NI) {
      VMC4;
    } else {
      VMC0;
    }
    __builtin_amdgcn_s_barrier();
    const char* base = sbuf + cur * 16384;
    bf16x8 af[4], bv[4];
#pragma unroll
    for (int i = 0; i < 4; ++i)
      af[i] = *(const bf16x8*)(base + ((wr * 64 + i * 16 + l15) * 32 + 8 * g) * 2);
#pragma unroll
    for (int i = 0; i < 4; ++i)
      bv[i] = *(const bf16x8*)(base + 8192 + ((wc * 64 + i * 16 + l15) * 32 + 8 * g) * 2);
#pragma unroll
    for (int mi = 0; mi < 4; ++mi)
#pragma unroll
      for (int ni = 0; ni < 4; ++ni)
        acc[mi][ni] = __builtin_amdgcn_mfma_f32_16x16x32_bf16(af[mi], bv[ni], acc[mi][ni], 0, 0, 0);
    __builtin_amdgcn_s_barrier();
  }

  if constexpr (!L0) {
    if (tid < 128) {
      const int row = m0 + tid;
      float s = 0.f, q = 0.f;
#pragma unroll
      for (int j = 0; j < 8; ++j) {
        s += pIn[(size_t)j * MROWS + row];
        q += pIn[(size_t)(8 + j) * MROWS + row];
      }
      const float mean = s * (1.0f / 512.0f);
      const float var = q * (1.0f / 512.0f) - mean * mean;
      const float rs = rsqrtf(var + 1e-6f);
      rsL[tid] = rs;
      rsmL[tid] = rs * mean;
    }
    __syncthreads();
  }

  const bool VPATH = (EPI == 0) && (n0 >= 1024);
#pragma unroll
  for (int mi = 0; mi < 4; ++mi)
#pragma unroll
    for (int nf = 0; nf < 4; ++nf) {
      const int lr = wr * 64 + mi * 16 + 4 * g;
      const int row = m0 + lr;
      const int col = n0 + wc * 64 + nf * 16 + l15;
      float vgc = 0.f, vbc = 0.f, bc = 0.f;
      if constexpr (!L0) { vgc = vg[col]; vbc = vb[col]; }
      if constexpr (EPI == 1) bc = bias[col];
      float val[4];
#pragma unroll
      for (int r = 0; r < 4; ++r) {
        float a = acc[mi][nf][r];
        float v;
        if constexpr (L0) v = a;
        else v = rsL[lr + r] * a - rsmL[lr + r] * vgc + vbc;
        if constexpr (EPI == 1) v = gelu_f(v + bc);
        val[r] = v;
      }
      if (VPATH) {
        const int cv = col - 1024, hh = cv >> 6, dd = cv & 63;
        const int b = row / SEQL, s = row % SEQL;
        bf16x4 q4;
#pragma unroll
        for (int r = 0; r < 4; ++r) q4[r] = (bf16)val[r];
        *(bf16x4*)&vT[(size_t)((b * 8 + hh) * 64 + dd) * SEQL + s] = q4;
      } else {
#pragma unroll
        for (int r = 0; r < 4; ++r)
          C[(size_t)(row + r) * N + col] = (bf16)val[r];
      }
    }
}

// =========================================================================
// 128^2 GEMM, 3-stage counted-vmcnt(8), LN-fused epilogue (Wo / FFN2).
// =========================================================================
template <int EPI, int KT>
__global__ __launch_bounds__(256) void gemm_fuse(const bf16* __restrict__ A,
                                                 const bf16* __restrict__ Bt,
                                                 const bf16* __restrict__ zgIn,
                                                 const float* __restrict__ pIn,
                                                 const float* __restrict__ vg_in,
                                                 const float* __restrict__ vb_in,
                                                 const float* __restrict__ extra_b,
                                                 const float* __restrict__ g_out,
                                                 bf16* __restrict__ zgOut,
                                                 float* __restrict__ pOut) {
  constexpr int N = 512;
  constexpr int K = KT;
  constexpr int NI = K >> 5;
  __shared__ char sbuf[49152];
  __shared__ float rsL[128], rsmL[128];
  const int tid = threadIdx.x;
  const int lane = tid & 63, w = tid >> 6;
  const int wr = w >> 1, wc = w & 1;
  const int l15 = lane & 15, g = lane >> 4;
  const int m0 = blockIdx.y * 128, n0 = blockIdx.x * 128;
  f32x4 acc[4][4] = {};
  const int rr0 = tid >> 2, kc = tid & 3;
  const bf16* Ap0 = A + (size_t)(m0 + rr0) * K + kc * 8;
  const bf16* Ap1 = A + (size_t)(m0 + 64 + rr0) * K + kc * 8;
  const bf16* Bp0 = Bt + (size_t)(n0 + rr0) * K + kc * 8;
  const bf16* Bp1 = Bt + (size_t)(n0 + 64 + rr0) * K + kc * 8;

  auto STAGE = [&](int st, int kt) {
    char* base = sbuf + st * 16384;
    gll16(Ap0 + kt, base + tid * 16);
    gll16(Ap1 + kt, base + 4096 + tid * 16);
    gll16(Bp0 + kt, base + 8192 + tid * 16);
    gll16(Bp1 + kt, base + 12288 + tid * 16);
  };

  STAGE(0, 0);
  STAGE(1, 32);
#pragma unroll 3
  for (int it = 0; it < NI; ++it) {
    const int cur = it % 3;
    if (it + 2 < NI) {
      STAGE((it + 2) % 3, (it + 2) * 32);
      VMC8;
    } else if (it + 1 < NI) {
      VMC4;
    } else {
      VMC0;
    }
    __builtin_amdgcn_s_barrier();
    const char* base = sbuf + cur * 16384;
    bf16x8 af[4], bv[4];
#pragma unroll
    for (int i = 0; i < 4; ++i)
      af[i] = *(const bf16x8*)(base + ((wr * 64 + i * 16 + l15) * 32 + 8 * g) * 2);
#pragma unroll
    for (int i = 0; i < 4; ++i)
      bv[i] = *(const bf16x8*)(base + 8192 + ((wc * 64 + i * 16 + l15) * 32 + 8 * g) * 2);
#pragma unroll
    for (int mi = 0; mi < 4; ++mi)
#pragma unroll
      for (int ni = 0; ni < 4; ++ni)
        acc[mi][ni] = __builtin_amdgcn_mfma_f32_16x16x32_bf16(af[mi], bv[ni], acc[mi][ni], 0, 0, 0);
    __builtin_amdgcn_s_barrier();
  }

  bf16* ztile = (bf16*)sbuf;
#pragma unroll
  for (int j = 0; j < 8; ++j) {
    const int row = j * 16 + (tid >> 4);
    const bf16* gsrc = zgIn + (size_t)(m0 + row) * N + n0 + (tid & 15) * 8;
    gll16(gsrc, sbuf + j * 4096 + tid * 16);
  }

  if constexpr (EPI != 0) {
    if (tid < 128) {
      const int row = m0 + tid;
      float s = 0.f, q = 0.f;
#pragma unroll
      for (int j = 0; j < 8; ++j) {
        s += pIn[(size_t)j * MROWS + row];
        q += pIn[(size_t)(8 + j) * MROWS + row];
      }
      const float mean = s * (1.0f / 512.0f);
      const float var = q * (1.0f / 512.0f) - mean * mean;
      const float rs = rsqrtf(var + 1e-6f);
      rsL[tid] = rs;
      rsmL[tid] = rs * mean;
    }
  }
  VMC0;
  __syncthreads();

  const int nb = n0 >> 7;
  float vgc[4], vbc[4], go[4], eb[4];
#pragma unroll
  for (int ni = 0; ni < 4; ++ni) {
    const int col = n0 + wc * 64 + ni * 16 + l15;
    if constexpr (EPI != 0) { vgc[ni] = vg_in[col]; vbc[ni] = vb_in[col]; }
    go[ni] = g_out[col];
    if constexpr (EPI == 2) eb[ni] = extra_b[col];
  }
#pragma unroll
  for (int mi = 0; mi < 4; ++mi) {
#pragma unroll
    for (int rr = 0; rr < 4; ++rr) {
      const int lr = wr * 64 + mi * 16 + 4 * g + rr;
      const int row = m0 + lr;
      float s = 0.f, q = 0.f;
#pragma unroll
      for (int ni = 0; ni < 4; ++ni) {
        const int lc = wc * 64 + ni * 16 + l15;
        const float zgv = (float)ztile[lr * 128 + lc];
        float hprev;
        if constexpr (EPI == 0) hprev = zgv;
        else hprev = rsL[lr] * zgv - rsmL[lr] * vgc[ni] + vbc[ni];
        float z = acc[mi][ni][rr] + hprev;
        if constexpr (EPI == 2) z += eb[ni];
        s += z;
        q += z * z;
        ztile[lr * 128 + lc] = (bf16)(z * go[ni]);
      }
      s += __shfl_xor(s, 1); s += __shfl_xor(s, 2); s += __shfl_xor(s, 4); s += __shfl_xor(s, 8);
      q += __shfl_xor(q, 1); q += __shfl_xor(q, 2); q += __shfl_xor(q, 4); q += __shfl_xor(q, 8);
      if (l15 == 0) {
        pOut[(size_t)(nb * 2 + wc) * MROWS + row] = s;
        pOut[(size_t)(8 + nb * 2 + wc) * MROWS + row] = q;
      }
    }
  }
  __syncthreads();
#pragma unroll
  for (int i = 0; i < 8; ++i) {
    const int id = i * 256 + tid;
    const int row = id >> 4, c16 = id & 15;
    bf16x8 v = *(const bf16x8*)&ztile[row * 128 + c16 * 8];
    *(bf16x8*)&zgOut[(size_t)(m0 + row) * N + n0 + c16 * 8] = v;
  }
}

// =========================================================================
// Local attention: K/V tiles staged to LDS (coalesced + source-swizzled),
// P chunked through 10KB LDS. 74KB LDS -> 2 WGs/CU. (verified round-9)
// =========================================================================
template <int NKEY>
__device__ __forceinline__ void attn_body(int n, int h, int b,
                                          const bf16* __restrict__ Qb,
                                          const bf16* __restrict__ Kb,
                                          const bf16* __restrict__ Vt,
                                          bf16* __restrict__ O,
                                          bf16* __restrict__ Ks,
                                          bf16* __restrict__ Vs,
                                          bf16* __restrict__ Pc) {
  constexpr int NF = NKEY / 16;
  constexpr int KC = NKEY / 32;
  constexpr int VG = NKEY / 8;
  const int tid = threadIdx.x, w = tid >> 6, lane = tid & 63;
  const int l15 = lane & 15, g = lane >> 4;
  const int keybase = (NKEY == 128) ? 0 : (n - 1) * 128;
  const int qbase = n * 128;

#pragma unroll
  for (int p = 0; p < NKEY / 64; ++p) {
    const int j = p * 512 + tid;
    const int row = j >> 3, lg = j & 7;
    const int pg = lg ^ (row & 7);
    gll16(Kb + (size_t)(b * SEQL + keybase + row) * QKVS + h * 64 + pg * 8, Ks + j * 8);
  }
#pragma unroll
  for (int p = 0; p < NKEY / 64; ++p) {
    const int j = p * 512 + tid;
    const int row = j / VG, lg = j % VG;
    const int pg = lg ^ (row & (VG - 1));
    gll16(Vt + (size_t)((b * 8 + h) * 64 + row) * SEQL + keybase + pg * 8, Vs + j * 8);
  }

  const bf16* qrow = Qb + (size_t)(b * SEQL + qbase + w * 16 + l15) * QKVS + h * 64;
  bf16x8 qf0 = *(const bf16x8*)(qrow + 8 * g);
  bf16x8 qf1 = *(const bf16x8*)(qrow + 32 + 8 * g);

  VMC0;
  __syncthreads();

  f32x4 S[NF];
#pragma unroll
  for (int nf = 0; nf < NF; ++nf) S[nf] = f32x4{0.f, 0.f, 0.f, 0.f};
#pragma unroll
  for (int nf = 0; nf < NF; ++nf) {
    const int krow = nf * 16 + l15;
    const int pg0 = g ^ (krow & 7);
    const int pg1 = (g + 4) ^ (krow & 7);
    bf16x8 kf0 = *(const bf16x8*)&Ks[krow * 64 + pg0 * 8];
    bf16x8 kf1 = *(const bf16x8*)&Ks[krow * 64 + pg1 * 8];
    S[nf] = __builtin_amdgcn_mfma_f32_16x16x32_bf16(qf0, kf0, S[nf], 0, 0, 0);
    S[nf] = __builtin_amdgcn_mfma_f32_16x16x32_bf16(qf1, kf1, S[nf], 0, 0, 0);
  }
#pragma unroll
  for (int rr = 0; rr < 4; ++rr) {
    const int qloc = w * 16 + 4 * g + rr;
    float mx = -3.0e38f;
#pragma unroll
    for (int nf = 0; nf < NF; ++nf) {
      const int key = nf * 16 + l15;
      const bool valid = (NKEY == 128) ? (key <= qloc) : (key <= qloc + 128);
      float v = valid ? S[nf][rr] * 0.125f : -1.0e9f;
      S[nf][rr] = v;
      mx = fmaxf(mx, v);
    }
    mx = fmaxf(mx, __shfl_xor(mx, 1));
    mx = fmaxf(mx, __shfl_xor(mx, 2));
    mx = fmaxf(mx, __shfl_xor(mx, 4));
    mx = fmaxf(mx, __shfl_xor(mx, 8));
    float sden = 0.f;
#pragma unroll
    for (int nf = 0; nf < NF; ++nf) {
      float e = expf(S[nf][rr] - mx);
      S[nf][rr] = e;
      sden += e;
    }
    sden += __shfl_xor(sden, 1);
    sden += __shfl_xor(sden, 2);
    sden += __shfl_xor(sden, 4);
    sden += __shfl_xor(sden, 8);
    const float rcp = 1.0f / sden;
#pragma unroll
    for (int nf = 0; nf < NF; ++nf) S[nf][rr] *= rcp;
  }

  bf16* pcw = Pc + w * 640;
  f32x4 Oacc[4];
#pragma unroll
  for (int i = 0; i < 4; ++i) Oacc[i] = f32x4{0.f, 0.f, 0.f, 0.f};
#pragma unroll
  for (int kc = 0; kc < KC; ++kc) {
#pragma unroll
    for (int rr = 0; rr < 4; ++rr) {
      pcw[(4 * g + rr) * 40 + l15] = (bf16)S[2 * kc][rr];
      pcw[(4 * g + rr) * 40 + 16 + l15] = (bf16)S[2 * kc + 1][rr];
    }
    bf16x8 pa = *(const bf16x8*)&pcw[l15 * 40 + 8 * g];
#pragma unroll
    for (int nf = 0; nf < 4; ++nf) {
      const int vrow = nf * 16 + l15;
      const int pg = (kc * 4 + g) ^ (vrow & (VG - 1));
      bf16x8 vf = *(const bf16x8*)&Vs[vrow * NKEY + pg * 8];
      Oacc[nf] = __builtin_amdgcn_mfma_f32_16x16x32_bf16(pa, vf, Oacc[nf], 0, 0, 0);
    }
  }
#pragma unroll
  for (int nf = 0; nf < 4; ++nf)
#pragma unroll
    for (int rr = 0; rr < 4; ++rr)
      O[(size_t)(b * SEQL + qbase + w * 16 + 4 * g + rr) * HIDD + h * 64 + nf * 16 + l15] =
          (bf16)Oacc[nf][rr];
}

__global__ __launch_bounds__(512, 4) void attn_all(const bf16* __restrict__ Qb,
                                                   const bf16* __restrict__ Kb,
                                                   const bf16* __restrict__ Vt,
                                                   bf16* __restrict__ O) {
  __shared__ bf16 Ks[256 * 64];
  __shared__ bf16 Vs[64 * 256];
  __shared__ bf16 Pc[8 * 640];
  const int n = blockIdx.x, h = blockIdx.y, b = blockIdx.z;
  if (n == 0)
    attn_body<128>(0, h, b, Qb, Kb, Vt, O, Ks, Vs, Pc);
  else
    attn_body<256>(n, h, b, Qb, Kb, Vt, O, Ks, Vs, Pc);
}

// ---------------- final projection (input = recon LN of zg2) ----------------
__global__ __launch_bounds__(256) void proj_partial(const bf16* __restrict__ zg2,
                                                    const float* __restrict__ pSQ2,
                                                    const float* __restrict__ g5,
                                                    const float* __restrict__ b5,
                                                    const float* __restrict__ W,
                                                    float* __restrict__ part) {
  const int kc = blockIdx.x;
  const int t = threadIdx.x;
  __shared__ float Al[512 * 20];
  __shared__ float gld[512], bld[512], rsP[16], rsmP[16];
  gld[t] = g5[t]; gld[t + 256] = g5[t + 256];
  bld[t] = b5[t]; bld[t + 256] = b5[t + 256];
  if (t < 16) {
    const int row = t * SEQL + kc;
    float s = 0.f, q = 0.f;
#pragma unroll
    for (int j = 0; j < 8; ++j) {
      s += pSQ2[(size_t)j * MROWS + row];
      q += pSQ2[(size_t)(8 + j) * MROWS + row];
    }
    const float mean = s * (1.0f / 512.0f);
    const float var = q * (1.0f / 512.0f) - mean * mean;
    const float rs = rsqrtf(var + 1e-6f);
    rsP[t] = rs;
    rsmP[t] = rs * mean;
  }
  __syncthreads();
#pragma unroll
  for (int i = 0; i < 32; ++i) {
    int lin = i * 256 + t, m = lin >> 9, kk = lin & 511;
    const int row = m * SEQL + kc;
    Al[kk * 20 + m] = rsP[m] * (float)zg2[(size_t)row * 512 + kk] - rsmP[m] * gld[kk] + bld[kk];
  }
  __syncthreads();
  const size_t k0 = (size_t)kc * 512;
  float acc[16] = {};
  for (int kk = 0; kk < 512; ++kk) {
    const float wv = W[(k0 + kk) * 256 + t];
    const f32x4* a = (const f32x4*)&Al[kk * 20];
#pragma unroll
    for (int j = 0; j < 4; ++j) {
      f32x4 av = a[j];
      acc[j * 4 + 0] += av[0] * wv;
      acc[j * 4 + 1] += av[1] * wv;
      acc[j * 4 + 2] += av[2] * wv;
      acc[j * 4 + 3] += av[3] * wv;
    }
  }
#pragma unroll
  for (int m = 0; m < 16; ++m) part[(size_t)kc * 4096 + m * 256 + t] = acc[m];
}

__global__ __launch_bounds__(256) void proj_reduce1(const float* __restrict__ part,
                                                    float* __restrict__ part2) {
  const int i = blockIdx.x * 256 + threadIdx.x;
  const int cb = blockIdx.y;
  float s = 0.f;
  for (int c = cb * 64; c < cb * 64 + 64; ++c) s += part[(size_t)c * 4096 + i];
  part2[(size_t)cb * 4096 + i] = s;
}

__global__ __launch_bounds__(256) void proj_final(const float* __restrict__ part2,
                                                  const float* __restrict__ g,
                                                  const float* __restrict__ bt,
                                                  float* __restrict__ out) {
  const int row = blockIdx.x, t = threadIdx.x;
  float v = 0.f;
#pragma unroll
  for (int c = 0; c < 12; ++c) v += part2[(size_t)c * 4096 + row * 256 + t];
  const float x = gelu_f(v);
  __shared__ float red[256];
  red[t] = x;
  __syncthreads();
  for (int off = 128; off > 0; off >>= 1) {
    if (t < off) red[t] += red[t + off];
    __syncthreads();
  }
  const float mean = red[0] * (1.0f / 256.0f);
  __syncthreads();
  const float dx = x - mean;
  red[t] = dx * dx;
  __syncthreads();
  for (int off = 128; off > 0; off >>= 1) {
    if (t < off) red[t] += red[t + off];
    __syncthreads();
  }
  const float var = red[0] * (1.0f / 256.0f);
  const float rs = rsqrtf(var + 1e-6f);
  out[row * 256 + t] = dx * rs * g[t] + bt[t];
}

extern "C" void kernel_launch(void* const* d_in, const int* in_sizes, int n_in,
                              void* d_out, int out_size, void* d_ws, size_t ws_size,
                              hipStream_t stream) {
  const float* X = (const float*)d_in[0];
  const float* ET = (const float*)d_in[1];
  const float* Wq = (const float*)d_in[2];
  const float* Wk = (const float*)d_in[3];
  const float* Wv = (const float*)d_in[4];
  const float* Wo = (const float*)d_in[5];
  const float* ln1g = (const float*)d_in[6];
  const float* ln1b = (const float*)d_in[7];
  const float* W1 = (const float*)d_in[8];
  const float* b1 = (const float*)d_in[9];
  const float* W2 = (const float*)d_in[10];
  const float* b2 = (const float*)d_in[11];
  const float* ln2g = (const float*)d_in[12];
  const float* ln2b = (const float*)d_in[13];
  const float* PW = (const float*)d_in[14];
  const float* og = (const float*)d_in[15];
  const float* obv = (const float*)d_in[16];
  float* out = (float*)d_out;

  char* p = (char*)d_ws;
  auto alloc = [&](size_t bytes) {
    char* r = p;
    p += (bytes + 255) & ~(size_t)255;
    return r;
  };
  bf16* Wqkvt = (bf16*)alloc((size_t)NLAYER * QKVS * 512 * 2);
  bf16* Wot = (bf16*)alloc((size_t)NLAYER * 512 * 512 * 2);
  bf16* W1t = (bf16*)alloc((size_t)NLAYER * 512 * 2048 * 2);
  bf16* W2t = (bf16*)alloc((size_t)NLAYER * 512 * 2048 * 2);
  float* vQg = (float*)alloc((size_t)NLAYER * QKVS * 4);
  float* vQb = (float*)alloc((size_t)NLAYER * QKVS * 4);
  float* vW1g = (float*)alloc((size_t)NLAYER * 2048 * 4);
  float* vW1b = (float*)alloc((size_t)NLAYER * 2048 * 4);
  bf16* zg2 = (bf16*)alloc((size_t)MROWS * HIDD * 2);
  bf16* zg1 = (bf16*)alloc((size_t)MROWS * HIDD * 2);
  float* pSQ1 = (float*)alloc((size_t)16 * MROWS * 4);
  float* pSQ2 = (float*)alloc((size_t)16 * MROWS * 4);
  bf16* qkvB = (bf16*)alloc((size_t)MROWS * QKVS * 2);
  bf16* vT = (bf16*)alloc((size_t)MROWS * HIDD * 2);
  bf16* aO = (bf16*)alloc((size_t)MROWS * HIDD * 2);
  bf16* mid = (bf16*)alloc((size_t)MROWS * 2048 * 2);
  float* part = (float*)alloc((size_t)768 * 4096 * 4);
  float* part2 = (float*)alloc((size_t)12 * 4096 * 4);
  (void)ws_size; (void)n_in; (void)in_sizes; (void)out_size;

  prep<<<24660, 256, 0, stream>>>(X, ET, Wq, Wk, Wv, Wo, W1, W2, ln1g, ln1b, ln2g, ln2b,
                                  Wqkvt, Wot, W1t, W2t, vQg, vQb, vW1g, vW1b, zg2);

  for (int i = 0; i < NLAYER; ++i) {
    const bf16* WqkvL = Wqkvt + (size_t)i * QKVS * 512;
    const bf16* WoL = Wot + (size_t)i * 512 * 512;
    const bf16* W1L = W1t + (size_t)i * 512 * 2048;
    const bf16* W2L = W2t + (size_t)i * 512 * 2048;
    if (i == 0)
      gemm2p<0, true, 512><<<dim3(12, 96), 256, 0, stream>>>(zg2, WqkvL, qkvB, vT, pSQ2,
                                                             vQg, vQb, nullptr, QKVS);
    else
      gemm2p<0, false, 512><<<dim3(12, 96), 256, 0, stream>>>(zg2, WqkvL, qkvB, vT, pSQ2,
                                                              vQg + i * QKVS, vQb + i * QKVS,
                                                              nullptr, QKVS);
    attn_all<<<dim3(6, 8, 16), 512, 0, stream>>>(qkvB, qkvB + 512, vT, aO);
    if (i == 0)
      gemm_fuse<0, 512><<<dim3(4, 96), 256, 0, stream>>>(aO, WoL, zg2, nullptr, nullptr,
                                                         nullptr, nullptr, ln1g, zg1, pSQ1);
    else
      gemm_fuse<1, 512><<<dim3(4, 96), 256, 0, stream>>>(aO, WoL, zg2, pSQ2,
                                                         ln2g + (i - 1) * 512,
                                                         ln2b + (i - 1) * 512, nullptr,
                                                         ln1g + i * 512, zg1, pSQ1);
    gemm2p<1, false, 512><<<dim3(16, 96), 256, 0, stream>>>(zg1, W1L, mid, nullptr, pSQ1,
                                                            vW1g + i * 2048, vW1b + i * 2048,
                                                            b1 + i * 2048, 2048);
    gemm_fuse<2, 2048><<<dim3(4, 96), 256, 0, stream>>>(mid, W2L, zg1, pSQ1, ln1g + i * 512,
                                                        ln1b + i * 512, b2 + i * 512,
                                                        ln2g + i * 512, zg2, pSQ2);
  }

  proj_partial<<<768, 256, 0, stream>>>(zg2, pSQ2, ln2g + 5 * 512, ln2b + 5 * 512, PW, part);
  proj_reduce1<<<dim3(16, 12), 256, 0, stream>>>(part, part2);
  proj_final<<<16, 256, 0, stream>>>(part2, og, obv, out);
}